// Round 1
// baseline (279.643 us; speedup 1.0000x reference)
//
#include <hip/hip_runtime.h>
#include <hip/hip_bf16.h>
#include <stdint.h>

typedef __bf16 bf16x8 __attribute__((ext_vector_type(8)));
typedef __bf16 bf16x4 __attribute__((ext_vector_type(4)));
typedef float f32x4 __attribute__((ext_vector_type(4)));

#define DMODEL 1024
#define SEQ    2048
#define NHEAD  16
#define DK     64
#define MTOT   4096
#define KDIM   1024

__device__ __forceinline__ void gl2lds16(const void* g, void* l) {
  __builtin_amdgcn_global_load_lds((__attribute__((address_space(1))) void*)(g),
                                   (__attribute__((address_space(3))) void*)(l),
                                   16, 0, 0);
}

// ---------------- prep: f32 -> bf16 convert ----------------
__global__ __launch_bounds__(256) void k_cvt_bf16(const float* __restrict__ in,
                                                  __bf16* __restrict__ out, int n4) {
  int i = blockIdx.x * 256 + threadIdx.x;
  if (i >= n4) return;
  const float4 v = ((const float4*)in)[i];
  bf16x4 o = { (__bf16)v.x, (__bf16)v.y, (__bf16)v.z, (__bf16)v.w };
  ((bf16x4*)out)[i] = o;
}

// ---------------- prep: W [K][N] f32 -> WT [N][K] bf16 ----------------
__global__ __launch_bounds__(256) void k_transpose_bf16(const float* __restrict__ W,
                                                        __bf16* __restrict__ WT) {
  __shared__ float tile[32][33];
  int n0 = blockIdx.x * 32, k0 = blockIdx.y * 32;
  int tx = threadIdx.x & 31, ty = threadIdx.x >> 5;
  #pragma unroll
  for (int i = ty; i < 32; i += 8)
    tile[i][tx] = W[(size_t)(k0 + i) * DMODEL + n0 + tx];
  __syncthreads();
  #pragma unroll
  for (int i = ty; i < 32; i += 8)
    WT[(size_t)(n0 + i) * DMODEL + k0 + tx] = (__bf16)tile[tx][i];
}

// ---------------- GEMM: C[4096x1024] = A[4096x1024] @ B (BT given as [N][K]) ----------------
// MODE 0/1: out bf16 -> [B,H,S,DK]   MODE 2: out bf16 -> VT [B,H,DK,S]   MODE 3: f32 row-major + bias
template <int MODE>
__global__ __launch_bounds__(256) void k_gemm(const __bf16* __restrict__ A,
                                              const __bf16* __restrict__ BT,
                                              const float* __restrict__ bias,
                                              void* __restrict__ Cout) {
  __shared__ __align__(16) __bf16 As[128 * 32];
  __shared__ __align__(16) __bf16 Bs[128 * 32];
  const int tid = threadIdx.x;
  const int lane = tid & 63;
  const int wv = tid >> 6;
  const int wm = wv >> 1, wn = wv & 1;
  const int m0 = blockIdx.y * 128, n0 = blockIdx.x * 128;
  const int lr = lane & 15, lg = lane >> 4;

  f32x4 acc[4][4] = {};

  for (int k0 = 0; k0 < KDIM; k0 += 32) {
    #pragma unroll
    for (int i = 0; i < 2; ++i) {
      int c = tid + i * 256;          // chunk 0..511, 16B each
      int row = c >> 2, seg = c & 3;
      gl2lds16(A + (size_t)(m0 + row) * KDIM + k0 + seg * 8, (char*)As + c * 16);
      gl2lds16(BT + (size_t)(n0 + row) * KDIM + k0 + seg * 8, (char*)Bs + c * 16);
    }
    __syncthreads();
    bf16x8 af[4], bfr[4];
    #pragma unroll
    for (int mi = 0; mi < 4; ++mi)
      af[mi] = *(const bf16x8*)&As[(wm * 64 + mi * 16 + lr) * 32 + lg * 8];
    #pragma unroll
    for (int ni = 0; ni < 4; ++ni)
      bfr[ni] = *(const bf16x8*)&Bs[(wn * 64 + ni * 16 + lr) * 32 + lg * 8];
    #pragma unroll
    for (int mi = 0; mi < 4; ++mi)
      #pragma unroll
      for (int ni = 0; ni < 4; ++ni)
        acc[mi][ni] = __builtin_amdgcn_mfma_f32_16x16x32_bf16(af[mi], bfr[ni], acc[mi][ni], 0, 0, 0);
    __syncthreads();
  }

  #pragma unroll
  for (int mi = 0; mi < 4; ++mi)
    #pragma unroll
    for (int ni = 0; ni < 4; ++ni) {
      const int col = n0 + wn * 64 + ni * 16 + lr;
      const float bv = bias[col];
      #pragma unroll
      for (int r = 0; r < 4; ++r) {
        const int row = m0 + wm * 64 + mi * 16 + lg * 4 + r;
        float v = acc[mi][ni][r] + bv;
        if (MODE == 3) {
          ((float*)Cout)[(size_t)row * DMODEL + col] = v;
        } else {
          const int b = row >> 11, s = row & (SEQ - 1);
          const int h = col >> 6, dd = col & (DK - 1);
          if (MODE == 2)
            ((__bf16*)Cout)[((size_t)(b * NHEAD + h) * DK + dd) * SEQ + s] = (__bf16)v;
          else
            ((__bf16*)Cout)[((size_t)(b * NHEAD + h) * SEQ + s) * DK + dd] = (__bf16)v;
        }
      }
    }
}

// ---------------- flash attention (causal), bf16 MFMA ----------------
// Q,K: [B,H,S,DK]  V: [B,H,DK,S] (transposed)  O: [B,S,D] bf16
__global__ __launch_bounds__(256) void k_attn(const __bf16* __restrict__ Q,
                                              const __bf16* __restrict__ Kt,
                                              const __bf16* __restrict__ Vt,
                                              const float* __restrict__ pmask,
                                              __bf16* __restrict__ O) {
  __shared__ __align__(16) __bf16 plds[4][32 * 64];
  const int lane = threadIdx.x & 63;
  const int wv = threadIdx.x >> 6;
  const int lr = lane & 15, lg = lane >> 4;
  const int bh = blockIdx.y;
  const int b = bh >> 4, h = bh & 15;
  const int R0 = blockIdx.x * 128 + wv * 32;  // this wave's first Q row

  const __bf16* Qb = Q + (size_t)bh * SEQ * DK;
  const __bf16* Kb = Kt + (size_t)bh * SEQ * DK;
  const __bf16* Vb = Vt + (size_t)bh * DK * SEQ;
  const float* pm = pmask + (size_t)b * SEQ;

  bf16x8 qf[2][2];
  #pragma unroll
  for (int rg = 0; rg < 2; ++rg)
    #pragma unroll
    for (int kk = 0; kk < 2; ++kk)
      qf[rg][kk] = *(const bf16x8*)&Qb[(size_t)(R0 + rg * 16 + lr) * DK + kk * 32 + lg * 8];

  float mrow[2][4], lrow[2][4];
  f32x4 oacc[2][4] = {};
  #pragma unroll
  for (int rg = 0; rg < 2; ++rg)
    #pragma unroll
    for (int r = 0; r < 4; ++r) { mrow[rg][r] = -1e30f; lrow[rg][r] = 0.f; }

  const int t_last = R0 >> 6;
  for (int t = 0; t <= t_last; ++t) {
    // ---- scores: S = Q K^T ----
    f32x4 sc[2][4];
    #pragma unroll
    for (int g = 0; g < 4; ++g) {
      const __bf16* krow = &Kb[(size_t)(t * 64 + g * 16 + lr) * DK + lg * 8];
      bf16x8 kf0 = *(const bf16x8*)krow;
      bf16x8 kf1 = *(const bf16x8*)(krow + 32);
      #pragma unroll
      for (int rg = 0; rg < 2; ++rg) {
        f32x4 a = {};
        a = __builtin_amdgcn_mfma_f32_16x16x32_bf16(qf[rg][0], kf0, a, 0, 0, 0);
        a = __builtin_amdgcn_mfma_f32_16x16x32_bf16(qf[rg][1], kf1, a, 0, 0, 0);
        sc[rg][g] = a;
      }
    }
    // ---- scale + padding mask + causal mask ----
    const bool edge = (t == t_last);
    #pragma unroll
    for (int g = 0; g < 4; ++g) {
      const int colg = t * 64 + g * 16 + lr;
      const float pmv = pm[colg];
      #pragma unroll
      for (int rg = 0; rg < 2; ++rg)
        #pragma unroll
        for (int r = 0; r < 4; ++r) {
          float s = sc[rg][g][r] * 0.125f + pmv;
          if (edge && (colg > R0 + rg * 16 + lg * 4 + r)) s = -1e30f;
          sc[rg][g][r] = s;
        }
    }
    // ---- online softmax per row-group ----
    #pragma unroll
    for (int rg = 0; rg < 2; ++rg) {
      float mnew[4], alpha[4];
      #pragma unroll
      for (int r = 0; r < 4; ++r) {
        float pmax = fmaxf(fmaxf(sc[rg][0][r], sc[rg][1][r]), fmaxf(sc[rg][2][r], sc[rg][3][r]));
        #pragma unroll
        for (int msk = 1; msk < 16; msk <<= 1)
          pmax = fmaxf(pmax, __shfl_xor(pmax, msk, 64));
        mnew[r] = fmaxf(mrow[rg][r], pmax);
        alpha[r] = __expf(mrow[rg][r] - mnew[r]);
        mrow[rg][r] = mnew[r];
      }
      float psum[4] = {0.f, 0.f, 0.f, 0.f};
      #pragma unroll
      for (int g = 0; g < 4; ++g)
        #pragma unroll
        for (int r = 0; r < 4; ++r) {
          float p = __expf(sc[rg][g][r] - mnew[r]);
          sc[rg][g][r] = p;
          psum[r] += p;
        }
      #pragma unroll
      for (int r = 0; r < 4; ++r) {
        #pragma unroll
        for (int msk = 1; msk < 16; msk <<= 1)
          psum[r] += __shfl_xor(psum[r], msk, 64);
        lrow[rg][r] = lrow[rg][r] * alpha[r] + psum[r];
      }
      #pragma unroll
      for (int og = 0; og < 4; ++og)
        #pragma unroll
        for (int r = 0; r < 4; ++r)
          oacc[rg][og][r] *= alpha[r];
      // write P (bf16) to wave-private LDS, XOR-swizzled (row&7)<<4
      #pragma unroll
      for (int g = 0; g < 4; ++g)
        #pragma unroll
        for (int r = 0; r < 4; ++r) {
          const int prow = rg * 16 + lg * 4 + r;
          const int pcol = g * 16 + lr;
          int byteoff = (prow * 64 + pcol) * 2;
          byteoff ^= (prow & 7) << 4;
          *(__bf16*)((char*)plds[wv] + byteoff) = (__bf16)sc[rg][g][r];
        }
    }
    // ---- PV: O += P V ----
    bf16x8 vf[4][2];
    #pragma unroll
    for (int og = 0; og < 4; ++og) {
      const __bf16* vrow = &Vb[(size_t)(og * 16 + lr) * SEQ + t * 64 + lg * 8];
      vf[og][0] = *(const bf16x8*)vrow;
      vf[og][1] = *(const bf16x8*)(vrow + 32);
    }
    #pragma unroll
    for (int rg = 0; rg < 2; ++rg) {
      const int prow = rg * 16 + lr;
      int byte0 = prow * 128 + lg * 16;
      int byte1 = byte0 + 64;
      byte0 ^= (prow & 7) << 4;
      byte1 ^= (prow & 7) << 4;
      bf16x8 pa0 = *(const bf16x8*)((char*)plds[wv] + byte0);
      bf16x8 pa1 = *(const bf16x8*)((char*)plds[wv] + byte1);
      #pragma unroll
      for (int og = 0; og < 4; ++og) {
        oacc[rg][og] = __builtin_amdgcn_mfma_f32_16x16x32_bf16(pa0, vf[og][0], oacc[rg][og], 0, 0, 0);
        oacc[rg][og] = __builtin_amdgcn_mfma_f32_16x16x32_bf16(pa1, vf[og][1], oacc[rg][og], 0, 0, 0);
      }
    }
  }

  // ---- epilogue: normalize, write O as [B,S,H*DK] bf16 ----
  #pragma unroll
  for (int rg = 0; rg < 2; ++rg)
    #pragma unroll
    for (int og = 0; og < 4; ++og)
      #pragma unroll
      for (int r = 0; r < 4; ++r) {
        const int row = R0 + rg * 16 + lg * 4 + r;
        const float v = oacc[rg][og][r] / lrow[rg][r];
        O[((size_t)b * SEQ + row) * DMODEL + h * DK + og * 16 + lr] = (__bf16)v;
      }
}

extern "C" void kernel_launch(void* const* d_in, const int* in_sizes, int n_in,
                              void* d_out, int out_size, void* d_ws, size_t ws_size,
                              hipStream_t stream) {
  (void)in_sizes; (void)n_in; (void)out_size; (void)ws_size;
  const float* query = (const float*)d_in[0];
  const float* key   = (const float*)d_in[1];
  const float* value = (const float*)d_in[2];
  const float* pmask = (const float*)d_in[3];
  const float* w_q = (const float*)d_in[5];
  const float* w_k = (const float*)d_in[6];
  const float* w_v = (const float*)d_in[7];
  const float* w_o = (const float*)d_in[8];
  const float* b_q = (const float*)d_in[9];
  const float* b_k = (const float*)d_in[10];
  const float* b_v = (const float*)d_in[11];
  const float* b_o = (const float*)d_in[12];

  __bf16* ws = (__bf16*)d_ws;
  const size_t WSZ = (size_t)DMODEL * DMODEL;  // 1M elems
  const size_t XSZ = (size_t)MTOT * DMODEL;    // 4M elems
  __bf16* WTq = ws;
  __bf16* WTk = WTq + WSZ;
  __bf16* WTv = WTk + WSZ;
  __bf16* WTo = WTv + WSZ;
  __bf16* Xq  = WTo + WSZ;
  __bf16* Xk  = Xq + XSZ;
  __bf16* Xv  = Xk + XSZ;
  __bf16* Qh  = Xv + XSZ;
  __bf16* Kh  = Qh + XSZ;
  __bf16* Vh  = Kh + XSZ;
  __bf16* Oh  = Xq;  // alias: Xq dead after q projection

  dim3 blk(256);
  k_cvt_bf16<<<4096, blk, 0, stream>>>(query, Xq, (int)(XSZ / 4));
  k_cvt_bf16<<<4096, blk, 0, stream>>>(key,   Xk, (int)(XSZ / 4));
  k_cvt_bf16<<<4096, blk, 0, stream>>>(value, Xv, (int)(XSZ / 4));
  k_transpose_bf16<<<dim3(32, 32), blk, 0, stream>>>(w_q, WTq);
  k_transpose_bf16<<<dim3(32, 32), blk, 0, stream>>>(w_k, WTk);
  k_transpose_bf16<<<dim3(32, 32), blk, 0, stream>>>(w_v, WTv);
  k_transpose_bf16<<<dim3(32, 32), blk, 0, stream>>>(w_o, WTo);

  k_gemm<0><<<dim3(8, 32), blk, 0, stream>>>(Xq, WTq, b_q, Qh);
  k_gemm<0><<<dim3(8, 32), blk, 0, stream>>>(Xk, WTk, b_k, Kh);
  k_gemm<2><<<dim3(8, 32), blk, 0, stream>>>(Xv, WTv, b_v, Vh);

  k_attn<<<dim3(16, 32), blk, 0, stream>>>(Qh, Kh, Vh, pmask, Oh);

  k_gemm<3><<<dim3(8, 32), blk, 0, stream>>>(Oh, WTo, b_o, d_out);
}

// Round 2
// 278.212 us; speedup vs baseline: 1.0051x; 1.0051x over previous
//
#include <hip/hip_runtime.h>
#include <hip/hip_bf16.h>
#include <stdint.h>

typedef __bf16 bf16x8 __attribute__((ext_vector_type(8)));
typedef __bf16 bf16x4 __attribute__((ext_vector_type(4)));
typedef float f32x4 __attribute__((ext_vector_type(4)));

#define DMODEL 1024
#define SEQ    2048
#define NHEAD  16
#define DK     64
#define MTOT   4096
#define KDIM   1024

__device__ __forceinline__ void gl2lds16(const void* g, void* l) {
  __builtin_amdgcn_global_load_lds((__attribute__((address_space(1))) void*)(g),
                                   (__attribute__((address_space(3))) void*)(l),
                                   16, 0, 0);
}

// ---------------- prep: f32 -> bf16 convert ----------------
__global__ __launch_bounds__(256) void k_cvt_bf16(const float* __restrict__ in,
                                                  __bf16* __restrict__ out, int n4) {
  int i = blockIdx.x * 256 + threadIdx.x;
  if (i >= n4) return;
  const float4 v = ((const float4*)in)[i];
  bf16x4 o = { (__bf16)v.x, (__bf16)v.y, (__bf16)v.z, (__bf16)v.w };
  ((bf16x4*)out)[i] = o;
}

// ---------------- prep: W [K][N] f32 -> WT [N][K] bf16 ----------------
__global__ __launch_bounds__(256) void k_transpose_bf16(const float* __restrict__ W,
                                                        __bf16* __restrict__ WT) {
  __shared__ float tile[32][33];
  int n0 = blockIdx.x * 32, k0 = blockIdx.y * 32;
  int tx = threadIdx.x & 31, ty = threadIdx.x >> 5;
  #pragma unroll
  for (int i = ty; i < 32; i += 8)
    tile[i][tx] = W[(size_t)(k0 + i) * DMODEL + n0 + tx];
  __syncthreads();
  #pragma unroll
  for (int i = ty; i < 32; i += 8)
    WT[(size_t)(n0 + i) * DMODEL + k0 + tx] = (__bf16)tile[tx][i];
}

// ---------------- GEMM: C[4096x1024] = A[4096x1024] @ B (BT given as [N][K]) ----------------
// MODE 0/1: out bf16 -> [B,H,S,DK]   MODE 2: out bf16 -> VT [B,H,DK,S]   MODE 3: f32 row-major + bias
template <int MODE>
__global__ __launch_bounds__(256) void k_gemm(const __bf16* __restrict__ A,
                                              const __bf16* __restrict__ BT,
                                              const float* __restrict__ bias,
                                              void* __restrict__ Cout) {
  __shared__ __align__(16) __bf16 As[128 * 32];
  __shared__ __align__(16) __bf16 Bs[128 * 32];
  const int tid = threadIdx.x;
  const int lane = tid & 63;
  const int wv = tid >> 6;
  const int wm = wv >> 1, wn = wv & 1;
  const int m0 = blockIdx.y * 128, n0 = blockIdx.x * 128;
  const int lr = lane & 15, lg = lane >> 4;

  f32x4 acc[4][4] = {};

  for (int k0 = 0; k0 < KDIM; k0 += 32) {
    #pragma unroll
    for (int i = 0; i < 2; ++i) {
      int c = tid + i * 256;          // chunk 0..511, 16B each
      int row = c >> 2, seg = c & 3;
      gl2lds16(A + (size_t)(m0 + row) * KDIM + k0 + seg * 8, (char*)As + c * 16);
      gl2lds16(BT + (size_t)(n0 + row) * KDIM + k0 + seg * 8, (char*)Bs + c * 16);
    }
    __syncthreads();
    bf16x8 af[4], bfr[4];
    #pragma unroll
    for (int mi = 0; mi < 4; ++mi)
      af[mi] = *(const bf16x8*)&As[(wm * 64 + mi * 16 + lr) * 32 + lg * 8];
    #pragma unroll
    for (int ni = 0; ni < 4; ++ni)
      bfr[ni] = *(const bf16x8*)&Bs[(wn * 64 + ni * 16 + lr) * 32 + lg * 8];
    #pragma unroll
    for (int mi = 0; mi < 4; ++mi)
      #pragma unroll
      for (int ni = 0; ni < 4; ++ni)
        acc[mi][ni] = __builtin_amdgcn_mfma_f32_16x16x32_bf16(af[mi], bfr[ni], acc[mi][ni], 0, 0, 0);
    __syncthreads();
  }

  #pragma unroll
  for (int mi = 0; mi < 4; ++mi)
    #pragma unroll
    for (int ni = 0; ni < 4; ++ni) {
      const int col = n0 + wn * 64 + ni * 16 + lr;
      const float bv = bias[col];
      #pragma unroll
      for (int r = 0; r < 4; ++r) {
        const int row = m0 + wm * 64 + mi * 16 + lg * 4 + r;
        float v = acc[mi][ni][r] + bv;
        if (MODE == 3) {
          ((float*)Cout)[(size_t)row * DMODEL + col] = v;
        } else {
          const int b = row >> 11, s = row & (SEQ - 1);
          const int h = col >> 6, dd = col & (DK - 1);
          if (MODE == 2)
            ((__bf16*)Cout)[((size_t)(b * NHEAD + h) * DK + dd) * SEQ + s] = (__bf16)v;
          else
            ((__bf16*)Cout)[((size_t)(b * NHEAD + h) * SEQ + s) * DK + dd] = (__bf16)v;
        }
      }
    }
}

// ---------------- flash attention (causal), swapped-QK^T, balanced pairs ----------------
// Q,K: [B,H,S,DK]  V: [B,H,DK,S] (transposed)  O: [B,S,D] bf16
// One wave (64 thr) per block. Wave handles Q chunks c and 127-c (16 rows each),
// sequentially -> every wave does exactly 33 KV tiles (perfect balance).
// Swapped QK^T: sc = mfma(K_frag, Q_frag) = S^T, so lane (lr,lg) owns q-row lr,
// kv cols {g*16+lg*4+r}. Row softmax = 15 in-reg ops + 2 shuffles.
__global__ __launch_bounds__(64) void k_attn(const __bf16* __restrict__ Q,
                                             const __bf16* __restrict__ Kt,
                                             const __bf16* __restrict__ Vt,
                                             const float* __restrict__ pmask,
                                             __bf16* __restrict__ O) {
  __shared__ __align__(16) __bf16 plds[16 * 64];  // 2 KB, wave-private
  const int lane = threadIdx.x;
  const int lr = lane & 15, lg = lane >> 4;
  const int bh = blockIdx.y;
  const int b = bh >> 4, h = bh & 15;

  const __bf16* Qb = Q + (size_t)bh * SEQ * DK;
  const __bf16* Kb = Kt + (size_t)bh * SEQ * DK;
  const __bf16* Vb = Vt + (size_t)bh * DK * SEQ;
  const float* pm = pmask + (size_t)b * SEQ;
  const float SCL = 0.125f * 1.44269504f;   // 1/sqrt(dk) * log2(e)
  const float L2E = 1.44269504f;

  #pragma unroll
  for (int half = 0; half < 2; ++half) {
    const int c = half ? (127 - blockIdx.x) : blockIdx.x;
    const int QR = c * 16;

    // Q B-frag: col j = lr (q-row), k = lg*8 (+32)
    const bf16x8 qf0 = *(const bf16x8*)&Qb[(size_t)(QR + lr) * DK + lg * 8];
    const bf16x8 qf1 = *(const bf16x8*)&Qb[(size_t)(QR + lr) * DK + 32 + lg * 8];

    float mrow = -1e30f, lrow = 0.f;   // for q-row = lr (log2 domain)
    f32x4 oacc[4] = {};                // [og]: row q=lg*4+r, col d=og*16+lr

    const int t_last = QR >> 6;
    for (int t = 0; t <= t_last; ++t) {
      const __bf16* kbase = Kb + (size_t)t * 64 * DK;
      // ---- S^T = K Q^T ----
      f32x4 sc[4];
      #pragma unroll
      for (int g = 0; g < 4; ++g) {
        const __bf16* krow = &kbase[(size_t)(g * 16 + lr) * DK + lg * 8];
        bf16x8 kf0 = *(const bf16x8*)krow;
        bf16x8 kf1 = *(const bf16x8*)(krow + 32);
        f32x4 a = {};
        a = __builtin_amdgcn_mfma_f32_16x16x32_bf16(kf0, qf0, a, 0, 0, 0);
        a = __builtin_amdgcn_mfma_f32_16x16x32_bf16(kf1, qf1, a, 0, 0, 0);
        sc[g] = a;   // sc[g][r] = S[q=lr][kv=t*64+g*16+lg*4+r] (unscaled)
      }
      // ---- issue V loads early (independent of softmax) ----
      bf16x8 vf[4][2];
      #pragma unroll
      for (int og = 0; og < 4; ++og) {
        const __bf16* vrow = &Vb[(size_t)(og * 16 + lr) * SEQ + t * 64 + lg * 8];
        vf[og][0] = *(const bf16x8*)vrow;
        vf[og][1] = *(const bf16x8*)(vrow + 32);
      }
      // ---- scale + masks (log2 domain) ----
      const bool edge = (t == t_last);
      #pragma unroll
      for (int g = 0; g < 4; ++g) {
        const float4 pmv = *(const float4*)&pm[t * 64 + g * 16 + lg * 4];
        const float pmf[4] = {pmv.x, pmv.y, pmv.z, pmv.w};
        #pragma unroll
        for (int r = 0; r < 4; ++r) {
          float s = sc[g][r] * SCL + pmf[r] * L2E;
          if (edge && (t * 64 + g * 16 + lg * 4 + r > QR + lr)) s = -1e30f;
          sc[g][r] = s;
        }
      }
      // ---- online softmax: lane owns full row lr ----
      float pmax = sc[0][0];
      #pragma unroll
      for (int g = 0; g < 4; ++g)
        #pragma unroll
        for (int r = 0; r < 4; ++r) pmax = fmaxf(pmax, sc[g][r]);
      pmax = fmaxf(pmax, __shfl_xor(pmax, 16, 64));
      pmax = fmaxf(pmax, __shfl_xor(pmax, 32, 64));
      const float mnew = fmaxf(mrow, pmax);
      const float alpha = exp2f(mrow - mnew);
      mrow = mnew;
      float psum = 0.f;
      #pragma unroll
      for (int g = 0; g < 4; ++g)
        #pragma unroll
        for (int r = 0; r < 4; ++r) {
          float p = exp2f(sc[g][r] - mnew);
          sc[g][r] = p;
          psum += p;
        }
      psum += __shfl_xor(psum, 16, 64);
      psum += __shfl_xor(psum, 32, 64);
      lrow = lrow * alpha + psum;
      // ---- rescale O by alpha of its rows (q = lg*4+r) ----
      #pragma unroll
      for (int r = 0; r < 4; ++r) {
        const float av = __shfl(alpha, lg * 4 + r, 64);
        #pragma unroll
        for (int og = 0; og < 4; ++og) oacc[og][r] *= av;
      }
      // ---- P -> LDS (bf16, b64 packed, XOR swizzle (row&7)<<4) ----
      #pragma unroll
      for (int g = 0; g < 4; ++g) {
        bf16x4 pk = { (__bf16)sc[g][0], (__bf16)sc[g][1], (__bf16)sc[g][2], (__bf16)sc[g][3] };
        const int byteoff = lr * 128 + ((g * 32 + lg * 8) ^ ((lr & 7) << 4));
        *(bf16x4*)((char*)plds + byteoff) = pk;
      }
      // ---- PV: O += P V  (A-frag row = lr = lane's q-row, k-slice from LDS) ----
      #pragma unroll
      for (int kk = 0; kk < 2; ++kk) {
        const int byteoff = lr * 128 + ((kk * 64 + lg * 16) ^ ((lr & 7) << 4));
        const bf16x8 pa = *(const bf16x8*)((char*)plds + byteoff);
        #pragma unroll
        for (int og = 0; og < 4; ++og)
          oacc[og] = __builtin_amdgcn_mfma_f32_16x16x32_bf16(pa, vf[og][kk], oacc[og], 0, 0, 0);
      }
    }

    // ---- epilogue: normalize, write O [B,S,H*DK] ----
    #pragma unroll
    for (int r = 0; r < 4; ++r) {
      const float lsh = __shfl(lrow, lg * 4 + r, 64);
      const float inv = 1.f / lsh;
      const int row = QR + lg * 4 + r;
      #pragma unroll
      for (int og = 0; og < 4; ++og)
        O[((size_t)b * SEQ + row) * DMODEL + h * DK + og * 16 + lr] = (__bf16)(oacc[og][r] * inv);
    }
  }
}

extern "C" void kernel_launch(void* const* d_in, const int* in_sizes, int n_in,
                              void* d_out, int out_size, void* d_ws, size_t ws_size,
                              hipStream_t stream) {
  (void)in_sizes; (void)n_in; (void)out_size; (void)ws_size;
  const float* query = (const float*)d_in[0];
  const float* key   = (const float*)d_in[1];
  const float* value = (const float*)d_in[2];
  const float* pmask = (const float*)d_in[3];
  const float* w_q = (const float*)d_in[5];
  const float* w_k = (const float*)d_in[6];
  const float* w_v = (const float*)d_in[7];
  const float* w_o = (const float*)d_in[8];
  const float* b_q = (const float*)d_in[9];
  const float* b_k = (const float*)d_in[10];
  const float* b_v = (const float*)d_in[11];
  const float* b_o = (const float*)d_in[12];

  __bf16* ws = (__bf16*)d_ws;
  const size_t WSZ = (size_t)DMODEL * DMODEL;  // 1M elems
  const size_t XSZ = (size_t)MTOT * DMODEL;    // 4M elems
  __bf16* WTq = ws;
  __bf16* WTk = WTq + WSZ;
  __bf16* WTv = WTk + WSZ;
  __bf16* WTo = WTv + WSZ;
  __bf16* Xq  = WTo + WSZ;
  __bf16* Xk  = Xq + XSZ;
  __bf16* Xv  = Xk + XSZ;
  __bf16* Qh  = Xv + XSZ;
  __bf16* Kh  = Qh + XSZ;
  __bf16* Vh  = Kh + XSZ;
  __bf16* Oh  = Xq;  // alias: Xq dead after q projection

  dim3 blk(256);
  k_cvt_bf16<<<4096, blk, 0, stream>>>(query, Xq, (int)(XSZ / 4));
  k_cvt_bf16<<<4096, blk, 0, stream>>>(key,   Xk, (int)(XSZ / 4));
  k_cvt_bf16<<<4096, blk, 0, stream>>>(value, Xv, (int)(XSZ / 4));
  k_transpose_bf16<<<dim3(32, 32), blk, 0, stream>>>(w_q, WTq);
  k_transpose_bf16<<<dim3(32, 32), blk, 0, stream>>>(w_k, WTk);
  k_transpose_bf16<<<dim3(32, 32), blk, 0, stream>>>(w_v, WTv);
  k_transpose_bf16<<<dim3(32, 32), blk, 0, stream>>>(w_o, WTo);

  k_gemm<0><<<dim3(8, 32), blk, 0, stream>>>(Xq, WTq, b_q, Qh);
  k_gemm<0><<<dim3(8, 32), blk, 0, stream>>>(Xk, WTk, b_k, Kh);
  k_gemm<2><<<dim3(8, 32), blk, 0, stream>>>(Xv, WTv, b_v, Vh);

  k_attn<<<dim3(64, 32), 64, 0, stream>>>(Qh, Kh, Vh, pmask, Oh);

  k_gemm<3><<<dim3(8, 32), blk, 0, stream>>>(Oh, WTo, b_o, d_out);
}

// Round 3
// 194.530 us; speedup vs baseline: 1.4375x; 1.4302x over previous
//
#include <hip/hip_runtime.h>
#include <hip/hip_bf16.h>
#include <stdint.h>

typedef __bf16 bf16x8 __attribute__((ext_vector_type(8)));
typedef __bf16 bf16x4 __attribute__((ext_vector_type(4)));
typedef float f32x4 __attribute__((ext_vector_type(4)));

#define DMODEL 1024
#define SEQ    2048
#define NHEAD  16
#define DK     64
#define MTOT   4096
#define KDIM   1024

__device__ __forceinline__ void gl2lds16(const void* g, void* l) {
  __builtin_amdgcn_global_load_lds((__attribute__((address_space(1))) void*)(g),
                                   (__attribute__((address_space(3))) void*)(l),
                                   16, 0, 0);
}

// ---------------- prep: f32 -> bf16 convert ----------------
__global__ __launch_bounds__(256) void k_cvt_bf16(const float* __restrict__ in,
                                                  __bf16* __restrict__ out, int n4) {
  int i = blockIdx.x * 256 + threadIdx.x;
  if (i >= n4) return;
  const float4 v = ((const float4*)in)[i];
  bf16x4 o = { (__bf16)v.x, (__bf16)v.y, (__bf16)v.z, (__bf16)v.w };
  ((bf16x4*)out)[i] = o;
}

// ---------------- prep: W [K][N] f32 -> WT [N][K] bf16 ----------------
__global__ __launch_bounds__(256) void k_transpose_bf16(const float* __restrict__ W,
                                                        __bf16* __restrict__ WT) {
  __shared__ float tile[32][33];
  int n0 = blockIdx.x * 32, k0 = blockIdx.y * 32;
  int tx = threadIdx.x & 31, ty = threadIdx.x >> 5;
  #pragma unroll
  for (int i = ty; i < 32; i += 8)
    tile[i][tx] = W[(size_t)(k0 + i) * DMODEL + n0 + tx];
  __syncthreads();
  #pragma unroll
  for (int i = ty; i < 32; i += 8)
    WT[(size_t)(n0 + i) * DMODEL + k0 + tx] = (__bf16)tile[tx][i];
}

// ---------------- GEMM: C[4096x1024] = A[4096x1024] @ B (BT given as [N][K]) ----------------
// MODE 0/1: out bf16 -> [B,H,S,DK]   MODE 2: out bf16 -> VT [B,H,DK,S]   MODE 3: f32 row-major + bias
template <int MODE>
__global__ __launch_bounds__(256) void k_gemm(const __bf16* __restrict__ A,
                                              const __bf16* __restrict__ BT,
                                              const float* __restrict__ bias,
                                              void* __restrict__ Cout) {
  __shared__ __align__(16) __bf16 As[128 * 32];
  __shared__ __align__(16) __bf16 Bs[128 * 32];
  const int tid = threadIdx.x;
  const int lane = tid & 63;
  const int wv = tid >> 6;
  const int wm = wv >> 1, wn = wv & 1;
  const int m0 = blockIdx.y * 128, n0 = blockIdx.x * 128;
  const int lr = lane & 15, lg = lane >> 4;

  f32x4 acc[4][4] = {};

  for (int k0 = 0; k0 < KDIM; k0 += 32) {
    #pragma unroll
    for (int i = 0; i < 2; ++i) {
      int c = tid + i * 256;          // chunk 0..511, 16B each
      int row = c >> 2, seg = c & 3;
      gl2lds16(A + (size_t)(m0 + row) * KDIM + k0 + seg * 8, (char*)As + c * 16);
      gl2lds16(BT + (size_t)(n0 + row) * KDIM + k0 + seg * 8, (char*)Bs + c * 16);
    }
    __syncthreads();
    bf16x8 af[4], bfr[4];
    #pragma unroll
    for (int mi = 0; mi < 4; ++mi)
      af[mi] = *(const bf16x8*)&As[(wm * 64 + mi * 16 + lr) * 32 + lg * 8];
    #pragma unroll
    for (int ni = 0; ni < 4; ++ni)
      bfr[ni] = *(const bf16x8*)&Bs[(wn * 64 + ni * 16 + lr) * 32 + lg * 8];
    #pragma unroll
    for (int mi = 0; mi < 4; ++mi)
      #pragma unroll
      for (int ni = 0; ni < 4; ++ni)
        acc[mi][ni] = __builtin_amdgcn_mfma_f32_16x16x32_bf16(af[mi], bfr[ni], acc[mi][ni], 0, 0, 0);
    __syncthreads();
  }

  #pragma unroll
  for (int mi = 0; mi < 4; ++mi)
    #pragma unroll
    for (int ni = 0; ni < 4; ++ni) {
      const int col = n0 + wn * 64 + ni * 16 + lr;
      const float bv = bias[col];
      #pragma unroll
      for (int r = 0; r < 4; ++r) {
        const int row = m0 + wm * 64 + mi * 16 + lg * 4 + r;
        float v = acc[mi][ni][r] + bv;
        if (MODE == 3) {
          ((float*)Cout)[(size_t)row * DMODEL + col] = v;
        } else {
          const int b = row >> 11, s = row & (SEQ - 1);
          const int h = col >> 6, dd = col & (DK - 1);
          if (MODE == 2)
            ((__bf16*)Cout)[((size_t)(b * NHEAD + h) * DK + dd) * SEQ + s] = (__bf16)v;
          else
            ((__bf16*)Cout)[((size_t)(b * NHEAD + h) * SEQ + s) * DK + dd] = (__bf16)v;
        }
      }
    }
}

// ---------------- flash attention (causal), 4-wave blocks, LDS-staged K/V ----------------
// Q,K: [B,H,S,DK]  V: [B,H,DK,S] (transposed)  O: [B,S,D] bf16
// Block = 256 thr (4 waves), handles 64-row Q chunks qb and 31-qb sequentially
// -> exactly 33 KV tiles per block (perfect balance). K/V tiles (64x64 bf16)
// double-buffered in LDS via global_load_lds, XOR-swizzled (x ^= (row&7)<<4)
// with pre-swizzled global source (linear LDS dest). XCD-bijective bid mapping
// pins all blocks of a bh to one XCD (K/V L2-resident: 4 bh x 512KB = 2MB).
// Swapped QK^T per wave: lane owns full q-row lr -> softmax = in-reg + 2 shfl.
__global__ __launch_bounds__(256, 2) void k_attn(const __bf16* __restrict__ Q,
                                                 const __bf16* __restrict__ Kt,
                                                 const __bf16* __restrict__ Vt,
                                                 const float* __restrict__ pmask,
                                                 __bf16* __restrict__ O) {
  __shared__ __align__(16) __bf16 Ks[2][64 * 64];   // 2 x 8KB
  __shared__ __align__(16) __bf16 Vs[2][64 * 64];   // 2 x 8KB
  __shared__ __align__(16) __bf16 plds[4][16 * 64]; // 4 x 2KB wave-private

  const int tid = threadIdx.x;
  const int lane = tid & 63, wv = tid >> 6;
  const int lr = lane & 15, lg = lane >> 4;

  // bid = xcd + 8*(slot*16 + pair): all 16 pair-blocks of bh=slot*8+xcd on XCD bid%8
  const int bid = blockIdx.x;
  const int xcd = bid & 7;
  const int rdec = bid >> 3;
  const int slot = rdec >> 4;   // 0..3
  const int pair = rdec & 15;   // 0..15
  const int bh = slot * 8 + xcd;
  const int b = bh >> 4, h = bh & 15;

  const __bf16* Qb = Q + (size_t)bh * SEQ * DK;
  const __bf16* Kb = Kt + (size_t)bh * SEQ * DK;
  const __bf16* Vb = Vt + (size_t)bh * DK * SEQ;
  const float* pm = pmask + (size_t)b * SEQ;
  const float SCL = 0.125f * 1.44269504f;   // 1/sqrt(dk) * log2(e)
  const float L2E = 1.44269504f;

  // stage K/V tile t into buffer buf: linear LDS dest, inverse-swizzled source
  auto stage = [&](int buf, int t) {
    #pragma unroll
    for (int i = 0; i < 2; ++i) {
      const int c = tid + i * 256;              // 512 x 16B chunks
      const int row = c >> 3;                   // 0..63
      const int sx = ((c & 7) * 16) ^ ((row & 7) << 4);
      gl2lds16((const char*)Kb + (size_t)(t * 64 + row) * 128 + sx,
               (char*)&Ks[buf][0] + c * 16);
      gl2lds16((const char*)Vb + (size_t)row * (SEQ * 2) + (size_t)t * 128 + sx,
               (char*)&Vs[buf][0] + c * 16);
    }
  };

  for (int half = 0; half < 2; ++half) {
    const int qb = half ? (31 - pair) : pair;   // 64-row Q chunk index
    const int nt = qb + 1;                      // causal KV tiles
    const int QR = qb * 64 + wv * 16;           // this wave's first Q row

    const bf16x8 qf0 = *(const bf16x8*)&Qb[(size_t)(QR + lr) * DK + lg * 8];
    const bf16x8 qf1 = *(const bf16x8*)&Qb[(size_t)(QR + lr) * DK + 32 + lg * 8];

    float mrow = -1e30f, lrow = 0.f;   // q-row = lr (log2 domain)
    f32x4 oacc[4] = {};                // [og]: row q=lg*4+r, col d=og*16+lr

    stage(0, 0);
    __syncthreads();
    int cur = 0;
    for (int t = 0; t < nt; ++t) {
      if (t + 1 < nt) stage(cur ^ 1, t + 1);
      // ---- S^T = K Q^T (K-frags from swizzled LDS) ----
      f32x4 sc[4];
      #pragma unroll
      for (int g = 0; g < 4; ++g) {
        const int krow = g * 16 + lr;
        const int ksw = (krow & 7) << 4;
        bf16x8 kf0 = *(const bf16x8*)((const char*)&Ks[cur][0] + krow * 128 + ((lg * 16) ^ ksw));
        bf16x8 kf1 = *(const bf16x8*)((const char*)&Ks[cur][0] + krow * 128 + ((64 + lg * 16) ^ ksw));
        f32x4 a = {};
        a = __builtin_amdgcn_mfma_f32_16x16x32_bf16(kf0, qf0, a, 0, 0, 0);
        a = __builtin_amdgcn_mfma_f32_16x16x32_bf16(kf1, qf1, a, 0, 0, 0);
        sc[g] = a;   // sc[g][r] = S[q=lr][kv=t*64+g*16+lg*4+r]
      }
      // ---- scale + masks (log2 domain) ----
      const bool edge = (t == nt - 1);
      #pragma unroll
      for (int g = 0; g < 4; ++g) {
        const float4 pmv = *(const float4*)&pm[t * 64 + g * 16 + lg * 4];
        const float pmf[4] = {pmv.x, pmv.y, pmv.z, pmv.w};
        #pragma unroll
        for (int r = 0; r < 4; ++r) {
          float s = sc[g][r] * SCL + pmf[r] * L2E;
          if (edge && (t * 64 + g * 16 + lg * 4 + r > QR + lr)) s = -1e30f;
          sc[g][r] = s;
        }
      }
      // ---- online softmax: lane owns full row lr ----
      float pmax = sc[0][0];
      #pragma unroll
      for (int g = 0; g < 4; ++g)
        #pragma unroll
        for (int r = 0; r < 4; ++r) pmax = fmaxf(pmax, sc[g][r]);
      pmax = fmaxf(pmax, __shfl_xor(pmax, 16, 64));
      pmax = fmaxf(pmax, __shfl_xor(pmax, 32, 64));
      const float mnew = fmaxf(mrow, pmax);
      const float alpha = exp2f(mrow - mnew);
      mrow = mnew;
      float psum = 0.f;
      #pragma unroll
      for (int g = 0; g < 4; ++g)
        #pragma unroll
        for (int r = 0; r < 4; ++r) {
          float p = exp2f(sc[g][r] - mnew);
          sc[g][r] = p;
          psum += p;
        }
      psum += __shfl_xor(psum, 16, 64);
      psum += __shfl_xor(psum, 32, 64);
      lrow = lrow * alpha + psum;
      // ---- rescale O rows (q = lg*4+r) ----
      #pragma unroll
      for (int r = 0; r < 4; ++r) {
        const float av = __shfl(alpha, lg * 4 + r, 64);
        #pragma unroll
        for (int og = 0; og < 4; ++og) oacc[og][r] *= av;
      }
      // ---- P -> wave-private LDS (bf16, XOR swizzle (row&7)<<4) ----
      #pragma unroll
      for (int g = 0; g < 4; ++g) {
        bf16x4 pk = { (__bf16)sc[g][0], (__bf16)sc[g][1], (__bf16)sc[g][2], (__bf16)sc[g][3] };
        const int byteoff = lr * 128 + ((g * 32 + lg * 8) ^ ((lr & 7) << 4));
        *(bf16x4*)((char*)plds[wv] + byteoff) = pk;
      }
      // ---- PV: O += P V (P rows from LDS, V-frags from swizzled LDS) ----
      #pragma unroll
      for (int kk = 0; kk < 2; ++kk) {
        const int pboff = lr * 128 + ((kk * 64 + lg * 16) ^ ((lr & 7) << 4));
        const bf16x8 pa = *(const bf16x8*)((char*)plds[wv] + pboff);
        #pragma unroll
        for (int og = 0; og < 4; ++og) {
          const int vrow = og * 16 + lr;
          const int vsw = (vrow & 7) << 4;
          const bf16x8 vf = *(const bf16x8*)((const char*)&Vs[cur][0] + vrow * 128 + ((kk * 64 + lg * 16) ^ vsw));
          oacc[og] = __builtin_amdgcn_mfma_f32_16x16x32_bf16(pa, vf, oacc[og], 0, 0, 0);
        }
      }
      __syncthreads();   // drains prefetch (vmcnt) + protects buffer swap
      cur ^= 1;
    }

    // ---- epilogue: normalize, write O [B,S,H*DK] ----
    #pragma unroll
    for (int r = 0; r < 4; ++r) {
      const float lsh = __shfl(lrow, lg * 4 + r, 64);
      const float inv = 1.f / lsh;
      const int row = QR + lg * 4 + r;
      #pragma unroll
      for (int og = 0; og < 4; ++og)
        O[((size_t)b * SEQ + row) * DMODEL + h * DK + og * 16 + lr] = (__bf16)(oacc[og][r] * inv);
    }
  }
}

extern "C" void kernel_launch(void* const* d_in, const int* in_sizes, int n_in,
                              void* d_out, int out_size, void* d_ws, size_t ws_size,
                              hipStream_t stream) {
  (void)in_sizes; (void)n_in; (void)out_size; (void)ws_size;
  const float* query = (const float*)d_in[0];
  const float* key   = (const float*)d_in[1];
  const float* value = (const float*)d_in[2];
  const float* pmask = (const float*)d_in[3];
  const float* w_q = (const float*)d_in[5];
  const float* w_k = (const float*)d_in[6];
  const float* w_v = (const float*)d_in[7];
  const float* w_o = (const float*)d_in[8];
  const float* b_q = (const float*)d_in[9];
  const float* b_k = (const float*)d_in[10];
  const float* b_v = (const float*)d_in[11];
  const float* b_o = (const float*)d_in[12];

  __bf16* ws = (__bf16*)d_ws;
  const size_t WSZ = (size_t)DMODEL * DMODEL;  // 1M elems
  const size_t XSZ = (size_t)MTOT * DMODEL;    // 4M elems
  __bf16* WTq = ws;
  __bf16* WTk = WTq + WSZ;
  __bf16* WTv = WTk + WSZ;
  __bf16* WTo = WTv + WSZ;
  __bf16* Xq  = WTo + WSZ;
  __bf16* Xk  = Xq + XSZ;
  __bf16* Xv  = Xk + XSZ;
  __bf16* Qh  = Xv + XSZ;
  __bf16* Kh  = Qh + XSZ;
  __bf16* Vh  = Kh + XSZ;
  __bf16* Oh  = Xq;  // alias: Xq dead after q projection

  dim3 blk(256);
  k_cvt_bf16<<<4096, blk, 0, stream>>>(query, Xq, (int)(XSZ / 4));
  k_cvt_bf16<<<4096, blk, 0, stream>>>(key,   Xk, (int)(XSZ / 4));
  k_cvt_bf16<<<4096, blk, 0, stream>>>(value, Xv, (int)(XSZ / 4));
  k_transpose_bf16<<<dim3(32, 32), blk, 0, stream>>>(w_q, WTq);
  k_transpose_bf16<<<dim3(32, 32), blk, 0, stream>>>(w_k, WTk);
  k_transpose_bf16<<<dim3(32, 32), blk, 0, stream>>>(w_v, WTv);
  k_transpose_bf16<<<dim3(32, 32), blk, 0, stream>>>(w_o, WTo);

  k_gemm<0><<<dim3(8, 32), blk, 0, stream>>>(Xq, WTq, b_q, Qh);
  k_gemm<0><<<dim3(8, 32), blk, 0, stream>>>(Xk, WTk, b_k, Kh);
  k_gemm<2><<<dim3(8, 32), blk, 0, stream>>>(Xv, WTv, b_v, Vh);

  k_attn<<<dim3(512), blk, 0, stream>>>(Qh, Kh, Vh, pmask, Oh);

  k_gemm<3><<<dim3(8, 32), blk, 0, stream>>>(Oh, WTo, b_o, d_out);
}

// Round 5
// 181.223 us; speedup vs baseline: 1.5431x; 1.0734x over previous
//
#include <hip/hip_runtime.h>
#include <hip/hip_bf16.h>
#include <stdint.h>

typedef __bf16 bf16x8 __attribute__((ext_vector_type(8)));
typedef __bf16 bf16x4 __attribute__((ext_vector_type(4)));
typedef float f32x4 __attribute__((ext_vector_type(4)));

#define DMODEL 1024
#define SEQ    2048
#define NHEAD  16
#define DK     64
#define MTOT   4096
#define KDIM   1024

// Explicit ISA-level drain: my wave's outstanding global_load_lds (vmcnt) and
// ds ops (lgkmcnt) complete before proceeding; combined with s_barrier this
// makes the staging double-buffer airtight regardless of compiler waitcnt
// placement (T3 recipe: the vmcnt(0)/lgkmcnt(0) before barrier is explicit).
#define DRAIN_VM_LGKM() asm volatile("s_waitcnt vmcnt(0) lgkmcnt(0)" ::: "memory")
#define DRAIN_LGKM()    asm volatile("s_waitcnt lgkmcnt(0)" ::: "memory")

__device__ __forceinline__ void gl2lds16(const void* g, void* l) {
  __builtin_amdgcn_global_load_lds((__attribute__((address_space(1))) void*)(g),
                                   (__attribute__((address_space(3))) void*)(l),
                                   16, 0, 0);
}

// ---------------- prep: f32 -> bf16 convert, q/k/v batched ----------------
__global__ __launch_bounds__(256) void k_cvt3(const float* __restrict__ q,
                                              const float* __restrict__ k,
                                              const float* __restrict__ v,
                                              __bf16* __restrict__ oq,
                                              __bf16* __restrict__ ok,
                                              __bf16* __restrict__ ov,
                                              int n4) {
  const int which = blockIdx.y;
  const float* in = which == 0 ? q : (which == 1 ? k : v);
  __bf16* out = which == 0 ? oq : (which == 1 ? ok : ov);
  const int i = blockIdx.x * 256 + threadIdx.x;
  if (i >= n4) return;
  const float4 f = ((const float4*)in)[i];
  bf16x4 o = { (__bf16)f.x, (__bf16)f.y, (__bf16)f.z, (__bf16)f.w };
  ((bf16x4*)out)[i] = o;
}

// ---------------- prep: W [K][N] f32 -> WT [N][K] bf16, 4 weights batched ----------------
__global__ __launch_bounds__(256) void k_transpose4(const float* __restrict__ w0,
                                                    const float* __restrict__ w1,
                                                    const float* __restrict__ w2,
                                                    const float* __restrict__ w3,
                                                    __bf16* __restrict__ t0,
                                                    __bf16* __restrict__ t1,
                                                    __bf16* __restrict__ t2,
                                                    __bf16* __restrict__ t3) {
  const int z = blockIdx.z;
  const float* W = z == 0 ? w0 : (z == 1 ? w1 : (z == 2 ? w2 : w3));
  __bf16* WT = z == 0 ? t0 : (z == 1 ? t1 : (z == 2 ? t2 : t3));
  __shared__ float tile[32][33];
  int n0 = blockIdx.x * 32, k0 = blockIdx.y * 32;
  int tx = threadIdx.x & 31, ty = threadIdx.x >> 5;
  #pragma unroll
  for (int i = ty; i < 32; i += 8)
    tile[i][tx] = W[(size_t)(k0 + i) * DMODEL + n0 + tx];
  __syncthreads();
  #pragma unroll
  for (int i = ty; i < 32; i += 8)
    WT[(size_t)(n0 + i) * DMODEL + k0 + tx] = (__bf16)tile[tx][i];
}

// ---------------- batched projection GEMM: z in {q,k,v} ----------------
// C[4096x1024] = A @ B (BT given [N][K]).  z=0/1 -> [B,H,S,DK]; z=2 -> VT [B,H,DK,S]
__global__ __launch_bounds__(256) void k_gemm_qkv(
    const __bf16* __restrict__ A0, const __bf16* __restrict__ A1, const __bf16* __restrict__ A2,
    const __bf16* __restrict__ W0, const __bf16* __restrict__ W1, const __bf16* __restrict__ W2,
    const float* __restrict__ bi0, const float* __restrict__ bi1, const float* __restrict__ bi2,
    __bf16* __restrict__ C0, __bf16* __restrict__ C1, __bf16* __restrict__ C2) {
  const int z = blockIdx.z;
  const __bf16* A  = z == 0 ? A0 : (z == 1 ? A1 : A2);
  const __bf16* BT = z == 0 ? W0 : (z == 1 ? W1 : W2);
  const float* bias = z == 0 ? bi0 : (z == 1 ? bi1 : bi2);
  __bf16* Cout = z == 0 ? C0 : (z == 1 ? C1 : C2);

  __shared__ __align__(16) __bf16 As[128 * 32];
  __shared__ __align__(16) __bf16 Bs[128 * 32];
  const int tid = threadIdx.x;
  const int lane = tid & 63;
  const int wv = tid >> 6;
  const int wm = wv >> 1, wn = wv & 1;
  const int m0 = blockIdx.y * 128, n0 = blockIdx.x * 128;
  const int lr = lane & 15, lg = lane >> 4;

  f32x4 acc[4][4] = {};

  for (int k0 = 0; k0 < KDIM; k0 += 32) {
    #pragma unroll
    for (int i = 0; i < 2; ++i) {
      int c = tid + i * 256;
      int row = c >> 2, seg = c & 3;
      gl2lds16(A + (size_t)(m0 + row) * KDIM + k0 + seg * 8, (char*)As + c * 16);
      gl2lds16(BT + (size_t)(n0 + row) * KDIM + k0 + seg * 8, (char*)Bs + c * 16);
    }
    DRAIN_VM_LGKM();
    __syncthreads();
    bf16x8 af[4], bfr[4];
    #pragma unroll
    for (int mi = 0; mi < 4; ++mi)
      af[mi] = *(const bf16x8*)&As[(wm * 64 + mi * 16 + lr) * 32 + lg * 8];
    #pragma unroll
    for (int ni = 0; ni < 4; ++ni)
      bfr[ni] = *(const bf16x8*)&Bs[(wn * 64 + ni * 16 + lr) * 32 + lg * 8];
    #pragma unroll
    for (int mi = 0; mi < 4; ++mi)
      #pragma unroll
      for (int ni = 0; ni < 4; ++ni)
        acc[mi][ni] = __builtin_amdgcn_mfma_f32_16x16x32_bf16(af[mi], bfr[ni], acc[mi][ni], 0, 0, 0);
    DRAIN_LGKM();
    __syncthreads();
  }

  #pragma unroll
  for (int mi = 0; mi < 4; ++mi)
    #pragma unroll
    for (int ni = 0; ni < 4; ++ni) {
      const int col = n0 + wn * 64 + ni * 16 + lr;
      const float bv = bias[col];
      #pragma unroll
      for (int r = 0; r < 4; ++r) {
        const int row = m0 + wm * 64 + mi * 16 + lg * 4 + r;
        float v = acc[mi][ni][r] + bv;
        const int b = row >> 11, s = row & (SEQ - 1);
        const int h = col >> 6, dd = col & (DK - 1);
        if (z == 2)
          Cout[((size_t)(b * NHEAD + h) * DK + dd) * SEQ + s] = (__bf16)v;
        else
          Cout[((size_t)(b * NHEAD + h) * SEQ + s) * DK + dd] = (__bf16)v;
      }
    }
}

// ---------------- final GEMM: f32 out + bias ----------------
__global__ __launch_bounds__(256) void k_gemm_out(const __bf16* __restrict__ A,
                                                  const __bf16* __restrict__ BT,
                                                  const float* __restrict__ bias,
                                                  float* __restrict__ Cout) {
  __shared__ __align__(16) __bf16 As[128 * 32];
  __shared__ __align__(16) __bf16 Bs[128 * 32];
  const int tid = threadIdx.x;
  const int lane = tid & 63;
  const int wv = tid >> 6;
  const int wm = wv >> 1, wn = wv & 1;
  const int m0 = blockIdx.y * 128, n0 = blockIdx.x * 128;
  const int lr = lane & 15, lg = lane >> 4;

  f32x4 acc[4][4] = {};

  for (int k0 = 0; k0 < KDIM; k0 += 32) {
    #pragma unroll
    for (int i = 0; i < 2; ++i) {
      int c = tid + i * 256;
      int row = c >> 2, seg = c & 3;
      gl2lds16(A + (size_t)(m0 + row) * KDIM + k0 + seg * 8, (char*)As + c * 16);
      gl2lds16(BT + (size_t)(n0 + row) * KDIM + k0 + seg * 8, (char*)Bs + c * 16);
    }
    DRAIN_VM_LGKM();
    __syncthreads();
    bf16x8 af[4], bfr[4];
    #pragma unroll
    for (int mi = 0; mi < 4; ++mi)
      af[mi] = *(const bf16x8*)&As[(wm * 64 + mi * 16 + lr) * 32 + lg * 8];
    #pragma unroll
    for (int ni = 0; ni < 4; ++ni)
      bfr[ni] = *(const bf16x8*)&Bs[(wn * 64 + ni * 16 + lr) * 32 + lg * 8];
    #pragma unroll
    for (int mi = 0; mi < 4; ++mi)
      #pragma unroll
      for (int ni = 0; ni < 4; ++ni)
        acc[mi][ni] = __builtin_amdgcn_mfma_f32_16x16x32_bf16(af[mi], bfr[ni], acc[mi][ni], 0, 0, 0);
    DRAIN_LGKM();
    __syncthreads();
  }

  #pragma unroll
  for (int mi = 0; mi < 4; ++mi)
    #pragma unroll
    for (int ni = 0; ni < 4; ++ni) {
      const int col = n0 + wn * 64 + ni * 16 + lr;
      const float bv = bias[col];
      #pragma unroll
      for (int r = 0; r < 4; ++r) {
        const int row = m0 + wm * 64 + mi * 16 + lg * 4 + r;
        Cout[(size_t)row * DMODEL + col] = acc[mi][ni][r] + bv;
      }
    }
}

// ---------------- flash attention (causal), 4-wave blocks, LDS-staged K/V ----------------
// Q,K: [B,H,S,DK]  V: [B,H,DK,S]  O: [B,S,D] bf16
// 1024 blocks (4/CU, LDS 40960x4 = 160KiB exact): block owns ONE 64-row Q chunk.
// LPT: qb descending in dispatch order. XCD-pinned: bid&7 = XCD, 4 bh per XCD.
// Explicit vmcnt/lgkm drains before each barrier make the double-buffer
// protocol airtight at ISA level (round-4 post-timing divergence fix).
__global__ __launch_bounds__(256, 4) void k_attn(const __bf16* __restrict__ Q,
                                                 const __bf16* __restrict__ Kt,
                                                 const __bf16* __restrict__ Vt,
                                                 const float* __restrict__ pmask,
                                                 __bf16* __restrict__ O) {
  __shared__ __align__(16) __bf16 Ks[2][64 * 64];   // 2 x 8KB
  __shared__ __align__(16) __bf16 Vs[2][64 * 64];   // 2 x 8KB
  __shared__ __align__(16) __bf16 plds[4][16 * 64]; // 4 x 2KB wave-private

  const int tid = threadIdx.x;
  const int lane = tid & 63, wv = tid >> 6;
  const int lr = lane & 15, lg = lane >> 4;

  const int bid = blockIdx.x;
  const int xcd = bid & 7;
  const int rdec = bid >> 3;      // 0..127
  const int slot = rdec >> 5;     // 0..3
  const int rank = rdec & 31;     // 0..31
  const int bh = slot * 8 + xcd;
  const int b = bh >> 4, h = bh & 15;
  const int qb = 31 - rank;       // LPT: largest chunk first

  const __bf16* Qb = Q + (size_t)bh * SEQ * DK;
  const __bf16* Kb = Kt + (size_t)bh * SEQ * DK;
  const __bf16* Vb = Vt + (size_t)bh * DK * SEQ;
  const float* pm = pmask + (size_t)b * SEQ;
  const float SCL = 0.125f * 1.44269504f;   // 1/sqrt(dk) * log2(e)
  const float L2E = 1.44269504f;

  auto stage = [&](int buf, int t) {
    #pragma unroll
    for (int i = 0; i < 2; ++i) {
      const int c = tid + i * 256;              // 512 x 16B chunks
      const int row = c >> 3;                   // 0..63
      const int sx = ((c & 7) * 16) ^ ((row & 7) << 4);
      gl2lds16((const char*)Kb + (size_t)(t * 64 + row) * 128 + sx,
               (char*)&Ks[buf][0] + c * 16);
      gl2lds16((const char*)Vb + (size_t)row * (SEQ * 2) + (size_t)t * 128 + sx,
               (char*)&Vs[buf][0] + c * 16);
    }
  };

  const int nt = qb + 1;
  const int QR = qb * 64 + wv * 16;

  const bf16x8 qf0 = *(const bf16x8*)&Qb[(size_t)(QR + lr) * DK + lg * 8];
  const bf16x8 qf1 = *(const bf16x8*)&Qb[(size_t)(QR + lr) * DK + 32 + lg * 8];

  float mrow = -1e30f, lrow = 0.f;   // q-row = lr (log2 domain)
  f32x4 oacc[4] = {};                // [og]: row q=lg*4+r, col d=og*16+lr

  stage(0, 0);
  DRAIN_VM_LGKM();
  __syncthreads();
  int cur = 0;
  for (int t = 0; t < nt; ++t) {
    if (t + 1 < nt) stage(cur ^ 1, t + 1);
    // ---- S^T = K Q^T (K-frags from swizzled LDS) ----
    f32x4 sc[4];
    #pragma unroll
    for (int g = 0; g < 4; ++g) {
      const int krow = g * 16 + lr;
      const int ksw = (krow & 7) << 4;
      bf16x8 kf0 = *(const bf16x8*)((const char*)&Ks[cur][0] + krow * 128 + ((lg * 16) ^ ksw));
      bf16x8 kf1 = *(const bf16x8*)((const char*)&Ks[cur][0] + krow * 128 + ((64 + lg * 16) ^ ksw));
      f32x4 a = {};
      a = __builtin_amdgcn_mfma_f32_16x16x32_bf16(kf0, qf0, a, 0, 0, 0);
      a = __builtin_amdgcn_mfma_f32_16x16x32_bf16(kf1, qf1, a, 0, 0, 0);
      sc[g] = a;   // sc[g][r] = S[q=lr][kv=t*64+g*16+lg*4+r]
    }
    // ---- scale + masks (log2 domain) ----
    const bool edge = (t == nt - 1);
    #pragma unroll
    for (int g = 0; g < 4; ++g) {
      const float4 pmv = *(const float4*)&pm[t * 64 + g * 16 + lg * 4];
      const float pmf[4] = {pmv.x, pmv.y, pmv.z, pmv.w};
      #pragma unroll
      for (int r = 0; r < 4; ++r) {
        float s = sc[g][r] * SCL + pmf[r] * L2E;
        if (edge && (t * 64 + g * 16 + lg * 4 + r > QR + lr)) s = -1e30f;
        sc[g][r] = s;
      }
    }
    // ---- online softmax: lane owns full row lr ----
    float pmax = sc[0][0];
    #pragma unroll
    for (int g = 0; g < 4; ++g)
      #pragma unroll
      for (int r = 0; r < 4; ++r) pmax = fmaxf(pmax, sc[g][r]);
    pmax = fmaxf(pmax, __shfl_xor(pmax, 16, 64));
    pmax = fmaxf(pmax, __shfl_xor(pmax, 32, 64));
    const float mnew = fmaxf(mrow, pmax);
    const float alpha = exp2f(mrow - mnew);
    mrow = mnew;
    float psum = 0.f;
    #pragma unroll
    for (int g = 0; g < 4; ++g)
      #pragma unroll
      for (int r = 0; r < 4; ++r) {
        float p = exp2f(sc[g][r] - mnew);
        sc[g][r] = p;
        psum += p;
      }
    psum += __shfl_xor(psum, 16, 64);
    psum += __shfl_xor(psum, 32, 64);
    lrow = lrow * alpha + psum;
    // ---- rescale O rows (q = lg*4+r) ----
    #pragma unroll
    for (int r = 0; r < 4; ++r) {
      const float av = __shfl(alpha, lg * 4 + r, 64);
      #pragma unroll
      for (int og = 0; og < 4; ++og) oacc[og][r] *= av;
    }
    // ---- P -> wave-private LDS (bf16, XOR swizzle (row&7)<<4) ----
    #pragma unroll
    for (int g = 0; g < 4; ++g) {
      bf16x4 pk = { (__bf16)sc[g][0], (__bf16)sc[g][1], (__bf16)sc[g][2], (__bf16)sc[g][3] };
      const int byteoff = lr * 128 + ((g * 32 + lg * 8) ^ ((lr & 7) << 4));
      *(bf16x4*)((char*)plds[wv] + byteoff) = pk;
    }
    // ---- PV: O += P V ----
    #pragma unroll
    for (int kk = 0; kk < 2; ++kk) {
      const int pboff = lr * 128 + ((kk * 64 + lg * 16) ^ ((lr & 7) << 4));
      const bf16x8 pa = *(const bf16x8*)((char*)plds[wv] + pboff);
      #pragma unroll
      for (int og = 0; og < 4; ++og) {
        const int vrow = og * 16 + lr;
        const int vsw = (vrow & 7) << 4;
        const bf16x8 vf = *(const bf16x8*)((const char*)&Vs[cur][0] + vrow * 128 + ((kk * 64 + lg * 16) ^ vsw));
        oacc[og] = __builtin_amdgcn_mfma_f32_16x16x32_bf16(pa, vf, oacc[og], 0, 0, 0);
      }
    }
    DRAIN_VM_LGKM();   // my stage loads landed (RAW for t+1) + my ds_reads done (WAR)
    __syncthreads();
    cur ^= 1;
  }

  // ---- epilogue: normalize, write O [B,S,H*DK] ----
  #pragma unroll
  for (int r = 0; r < 4; ++r) {
    const float lsh = __shfl(lrow, lg * 4 + r, 64);
    const float inv = 1.f / lsh;
    const int row = QR + lg * 4 + r;
    #pragma unroll
    for (int og = 0; og < 4; ++og)
      O[((size_t)b * SEQ + row) * DMODEL + h * DK + og * 16 + lr] = (__bf16)(oacc[og][r] * inv);
  }
}

extern "C" void kernel_launch(void* const* d_in, const int* in_sizes, int n_in,
                              void* d_out, int out_size, void* d_ws, size_t ws_size,
                              hipStream_t stream) {
  (void)in_sizes; (void)n_in; (void)out_size; (void)ws_size;
  const float* query = (const float*)d_in[0];
  const float* key   = (const float*)d_in[1];
  const float* value = (const float*)d_in[2];
  const float* pmask = (const float*)d_in[3];
  const float* w_q = (const float*)d_in[5];
  const float* w_k = (const float*)d_in[6];
  const float* w_v = (const float*)d_in[7];
  const float* w_o = (const float*)d_in[8];
  const float* b_q = (const float*)d_in[9];
  const float* b_k = (const float*)d_in[10];
  const float* b_v = (const float*)d_in[11];
  const float* b_o = (const float*)d_in[12];

  __bf16* ws = (__bf16*)d_ws;
  const size_t WSZ = (size_t)DMODEL * DMODEL;  // 1M elems
  const size_t XSZ = (size_t)MTOT * DMODEL;    // 4M elems
  __bf16* WTq = ws;
  __bf16* WTk = WTq + WSZ;
  __bf16* WTv = WTk + WSZ;
  __bf16* WTo = WTv + WSZ;
  __bf16* Xq  = WTo + WSZ;
  __bf16* Xk  = Xq + XSZ;
  __bf16* Xv  = Xk + XSZ;
  __bf16* Qh  = Xv + XSZ;
  __bf16* Kh  = Qh + XSZ;
  __bf16* Vh  = Kh + XSZ;
  __bf16* Oh  = Xq;  // alias: Xq dead after q projection

  dim3 blk(256);
  k_cvt3<<<dim3(4096, 3), blk, 0, stream>>>(query, key, value, Xq, Xk, Xv, (int)(XSZ / 4));
  k_transpose4<<<dim3(32, 32, 4), blk, 0, stream>>>(w_q, w_k, w_v, w_o, WTq, WTk, WTv, WTo);

  k_gemm_qkv<<<dim3(8, 32, 3), blk, 0, stream>>>(Xq, Xk, Xv, WTq, WTk, WTv,
                                                 b_q, b_k, b_v, Qh, Kh, Vh);

  k_attn<<<dim3(1024), blk, 0, stream>>>(Qh, Kh, Vh, pmask, Oh);

  k_gemm_out<<<dim3(8, 32), blk, 0, stream>>>(Oh, WTo, b_o, (float*)d_out);
}